// Round 14
// baseline (211.317 us; speedup 1.0000x reference)
//
#include <hip/hip_runtime.h>
#include <hip/hip_bf16.h>

#define B_   4
#define N_   2048
#define C_   1024
#define NT   32
#define QSCALE 0.18033688011112042f   // 0.125 * log2(e)

typedef __attribute__((ext_vector_type(8)))  short short8;
typedef __attribute__((ext_vector_type(4)))  float f32x4;
typedef __attribute__((ext_vector_type(16))) float f32x16;
typedef __attribute__((ext_vector_type(2)))  int   int2v;

__device__ __forceinline__ unsigned short f2bf(float x) {
    union { __hip_bfloat16 h; unsigned short u; } c;
    c.h = __float2bfloat16(x);
    return c.u;
}
__device__ __forceinline__ float fast_exp2(float x) {
    float r; asm("v_exp_f32 %0, %1" : "=v"(r) : "v"(x)); return r;
}
__device__ __forceinline__ int cvtpk(float a, float b) {
    int r; asm("v_cvt_pk_bf16_f32 %0, %1, %2" : "=v"(r) : "v"(a), "v"(b)); return r;
}

// ---- pre-pass: f32 [B,N,C] -> bf16 tiles in MFMA-FRAGMENT order ----
__global__ __launch_bounds__(256) void prepack(
    const float* __restrict__ K, const float* __restrict__ V,
    unsigned short* __restrict__ Kt, unsigned short* __restrict__ Vt)
{
    __shared__ __align__(16) unsigned short kl[4096];
    __shared__ __align__(16) unsigned short vl[4096];
    const int L = blockIdx.x;              // 2048
    const int xcd = L & 7;
    const int j = L >> 3;                  // 0..255
    const int head = xcd + 8 * (j >> 5);   // same head->XCD map as attn
    const int t = j & 31;
    const int b = head >> 4, h = head & 15;
    const int tid = threadIdx.x;
    const int r = tid >> 2, cb = tid & 3;
    const size_t head_off = (size_t)b * N_ * C_ + (size_t)h * 64;
    const int kv0 = t * 64;
    const int blk_out = head * NT + t;

    {
        const float* src = K + head_off + (size_t)(kv0 + r) * C_ + cb * 16;
        f32x4 x0 = *(const f32x4*)(src);
        f32x4 x1 = *(const f32x4*)(src + 4);
        f32x4 x2 = *(const f32x4*)(src + 8);
        f32x4 x3 = *(const f32x4*)(src + 12);
        short8 p0, p1;
        #pragma unroll
        for (int i = 0; i < 4; ++i) {
            p0[i] = (short)f2bf(x0[i]); p0[i + 4] = (short)f2bf(x1[i]);
            p1[i] = (short)f2bf(x2[i]); p1[i + 4] = (short)f2bf(x3[i]);
        }
        const int swz = (r & 7) << 3;
        *(short8*)&kl[r * 64 + ((cb * 16) ^ swz)]     = p0;
        *(short8*)&kl[r * 64 + ((cb * 16 + 8) ^ swz)] = p1;
    }
    {
        const float* src = V + head_off + (size_t)(kv0 + r) * C_ + cb * 16;
        f32x4 y0 = *(const f32x4*)(src);
        f32x4 y1 = *(const f32x4*)(src + 4);
        f32x4 y2 = *(const f32x4*)(src + 8);
        f32x4 y3 = *(const f32x4*)(src + 12);
        #pragma unroll
        for (int i = 0; i < 4; ++i) {
            int d0 = cb * 16 + i;
            vl[d0 * 64 + (r ^ ((d0 & 7) << 3))] = f2bf(y0[i]);
            int d1 = cb * 16 + 4 + i;
            vl[d1 * 64 + (r ^ ((d1 & 7) << 3))] = f2bf(y1[i]);
            int d2 = cb * 16 + 8 + i;
            vl[d2 * 64 + (r ^ ((d2 & 7) << 3))] = f2bf(y2[i]);
            int d3 = cb * 16 + 12 + i;
            vl[d3 * 64 + (r ^ ((d3 & 7) << 3))] = f2bf(y3[i]);
        }
    }
    __syncthreads();
    #pragma unroll
    for (int cc = 0; cc < 2; ++cc) {
        const int c  = tid + cc * 256;
        const int f  = c >> 6;
        const int ln = c & 63;
        const int row = (f & 1) * 32 + (ln & 31);
        const int col = (f >> 1) * 16 + (ln >> 5) * 8;
        const int sw  = (row & 7) << 3;
        short8 kk = *(const short8*)&kl[row * 64 + (col ^ sw)];
        short8 vv = *(const short8*)&vl[row * 64 + (col ^ sw)];
        *(short8*)&Kt[(size_t)blk_out * 4096 + c * 8] = kk;
        *(short8*)&Vt[(size_t)blk_out * 4096 + c * 8] = vv;
    }
}

#define MFMA32(A, B, C) __builtin_amdgcn_mfma_f32_32x32x16_bf16((A), (B), (C), 0, 0, 0)

// softmax head: max-tree + defer-max branch on SB (tile T-1's scores)
#define SM_HEAD(SB0, SB1, SMFIRST)                                             \
{                                                                              \
    float mx[8];                                                               \
    _Pragma("unroll")                                                          \
    for (int r = 0; r < 8; ++r)                                                \
        mx[r] = fmaxf(fmaxf(SB0[r], SB0[r + 8]), fmaxf(SB1[r], SB1[r + 8]));   \
    _Pragma("unroll")                                                          \
    for (int st = 4; st; st >>= 1) {                                           \
        _Pragma("unroll")                                                      \
        for (int r = 0; r < st; ++r) mx[r] = fmaxf(mx[r], mx[r + st]);         \
    }                                                                          \
    int2v msw = __builtin_amdgcn_permlane32_swap(                              \
        __float_as_int(mx[0]), __float_as_int(mx[0]), false, false);           \
    const float rmp = fmaxf(__int_as_float(msw[0]), __int_as_float(msw[1]));   \
    if (SMFIRST) {                                                             \
        m_r = rmp;                                                             \
        _Pragma("unroll")                                                      \
        for (int r = 0; r < 16; ++r) { SB0[r] -= rmp; SB1[r] -= rmp; }         \
    } else if (!__all(rmp <= 8.0f)) {                                          \
        const float d = fmaxf(rmp, 0.0f);                                      \
        const float corr = fast_exp2(-d);                                      \
        m_r += d;                                                              \
        l_half *= corr;                                                        \
        _Pragma("unroll")                                                      \
        for (int r = 0; r < 16; ++r) {                                         \
            SB0[r] -= d; SB1[r] -= d;                                          \
            o0[r] *= corr; o1[r] *= corr;                                      \
        }                                                                      \
    }                                                                          \
}

// softmax tail: exp in place, T12 pack -> pf0..3, sum-tree -> l_half
#define SM_TAIL(SB0, SB1)                                                      \
{                                                                              \
    _Pragma("unroll")                                                          \
    for (int r = 0; r < 16; ++r) {                                             \
        SB0[r] = fast_exp2(SB0[r]);                                            \
        SB1[r] = fast_exp2(SB1[r]);                                            \
    }                                                                          \
    {                                                                          \
        int w0, w1, w2, w3; int2v sA, sB;                                      \
        union { int i[4]; short8 v; } u;                                       \
        w0 = cvtpk(SB0[0], SB0[1]);   w1 = cvtpk(SB0[2], SB0[3]);              \
        w2 = cvtpk(SB0[4], SB0[5]);   w3 = cvtpk(SB0[6], SB0[7]);              \
        sA = __builtin_amdgcn_permlane32_swap(w0, w2, false, false);           \
        sB = __builtin_amdgcn_permlane32_swap(w1, w3, false, false);           \
        u.i[0] = sA[0]; u.i[1] = sB[0]; u.i[2] = sA[1]; u.i[3] = sB[1];        \
        pf0 = u.v;                                                             \
        w0 = cvtpk(SB0[8], SB0[9]);   w1 = cvtpk(SB0[10], SB0[11]);            \
        w2 = cvtpk(SB0[12], SB0[13]); w3 = cvtpk(SB0[14], SB0[15]);            \
        sA = __builtin_amdgcn_permlane32_swap(w0, w2, false, false);           \
        sB = __builtin_amdgcn_permlane32_swap(w1, w3, false, false);           \
        u.i[0] = sA[0]; u.i[1] = sB[0]; u.i[2] = sA[1]; u.i[3] = sB[1];        \
        pf1 = u.v;                                                             \
        w0 = cvtpk(SB1[0], SB1[1]);   w1 = cvtpk(SB1[2], SB1[3]);              \
        w2 = cvtpk(SB1[4], SB1[5]);   w3 = cvtpk(SB1[6], SB1[7]);              \
        sA = __builtin_amdgcn_permlane32_swap(w0, w2, false, false);           \
        sB = __builtin_amdgcn_permlane32_swap(w1, w3, false, false);           \
        u.i[0] = sA[0]; u.i[1] = sB[0]; u.i[2] = sA[1]; u.i[3] = sB[1];        \
        pf2 = u.v;                                                             \
        w0 = cvtpk(SB1[8], SB1[9]);   w1 = cvtpk(SB1[10], SB1[11]);            \
        w2 = cvtpk(SB1[12], SB1[13]); w3 = cvtpk(SB1[14], SB1[15]);            \
        sA = __builtin_amdgcn_permlane32_swap(w0, w2, false, false);           \
        sB = __builtin_amdgcn_permlane32_swap(w1, w3, false, false);           \
        u.i[0] = sA[0]; u.i[1] = sB[0]; u.i[2] = sA[1]; u.i[3] = sB[1];        \
        pf3 = u.v;                                                             \
    }                                                                          \
    float aa[8];                                                               \
    _Pragma("unroll")                                                          \
    for (int r = 0; r < 8; ++r)                                                \
        aa[r] = (SB0[r] + SB0[r + 8]) + (SB1[r] + SB1[r + 8]);                 \
    _Pragma("unroll")                                                          \
    for (int st = 4; st; st >>= 1) {                                           \
        _Pragma("unroll")                                                      \
        for (int r = 0; r < st; ++r) aa[r] += aa[r + st];                      \
    }                                                                          \
    l_half += aa[0];                                                           \
}

#define QK_SECTION(SA0, SA1)                                                   \
{                                                                              \
    const float nm = -m_r;                                                     \
    _Pragma("unroll")                                                          \
    for (int r = 0; r < 16; ++r) { SA0[r] = nm; SA1[r] = nm; }                 \
    const unsigned short* kl = &klds[cur][0];                                  \
    __builtin_amdgcn_s_setprio(1);                                             \
    short8 kf0 = *(const short8*)&kl[0 * 1024 + lofs];                         \
    short8 kf1 = *(const short8*)&kl[0 * 1024 + 512 + lofs];                   \
    SA0 = MFMA32(kf0, qfrag[0], SA0);                                          \
    SA1 = MFMA32(kf1, qfrag[0], SA1);                                          \
    kf0 = *(const short8*)&kl[1 * 1024 + lofs];                                \
    kf1 = *(const short8*)&kl[1 * 1024 + 512 + lofs];                          \
    SA0 = MFMA32(kf0, qfrag[1], SA0);                                          \
    SA1 = MFMA32(kf1, qfrag[1], SA1);                                          \
    kf0 = *(const short8*)&kl[2 * 1024 + lofs];                                \
    kf1 = *(const short8*)&kl[2 * 1024 + 512 + lofs];                          \
    SA0 = MFMA32(kf0, qfrag[2], SA0);                                          \
    SA1 = MFMA32(kf1, qfrag[2], SA1);                                          \
    kf0 = *(const short8*)&kl[3 * 1024 + lofs];                                \
    kf1 = *(const short8*)&kl[3 * 1024 + 512 + lofs];                          \
    SA0 = MFMA32(kf0, qfrag[3], SA0);                                          \
    SA1 = MFMA32(kf1, qfrag[3], SA1);                                          \
    __builtin_amdgcn_s_setprio(0);                                             \
}

#define PV_SECTION()                                                           \
{                                                                              \
    __builtin_amdgcn_s_setprio(1);                                             \
    o0 = MFMA32(vr0, pf0, o0);  o1 = MFMA32(vr1, pf0, o1);                     \
    o0 = MFMA32(vr2, pf1, o0);  o1 = MFMA32(vr3, pf1, o1);                     \
    o0 = MFMA32(vr4, pf2, o0);  o1 = MFMA32(vr5, pf2, o1);                     \
    o0 = MFMA32(vr6, pf3, o0);  o1 = MFMA32(vr7, pf3, o1);                     \
    __builtin_amdgcn_s_setprio(0);                                             \
}

#define V_LOAD(T)                                                              \
{                                                                              \
    const unsigned short* vtp = vbase + (size_t)(T) * 4096 + lofs;             \
    vr0 = *(const short8*)(vtp);         vr1 = *(const short8*)(vtp + 512);    \
    vr2 = *(const short8*)(vtp + 1024);  vr3 = *(const short8*)(vtp + 1536);   \
    vr4 = *(const short8*)(vtp + 2048);  vr5 = *(const short8*)(vtp + 2560);   \
    vr6 = *(const short8*)(vtp + 3072);  vr7 = *(const short8*)(vtp + 3584);   \
}

// 2-deep body: QK(T) into SA while softmax(T-1) on SB runs; then PV(T-1).
#define TILE_BODY2(T, SA0, SA1, SB0, SB1, SMFIRST)                             \
{                                                                              \
    asm volatile("s_waitcnt vmcnt(8) lgkmcnt(0)" ::: "memory");                \
    __builtin_amdgcn_s_barrier();                                              \
    if ((T) + 1 < NT) stageK((T) + 1, cur ^ 1);                                \
    SM_HEAD(SB0, SB1, SMFIRST)                                                 \
    QK_SECTION(SA0, SA1)                                                       \
    SM_TAIL(SB0, SB1)                                                          \
    PV_SECTION()                                                               \
    V_LOAD(T)                                                                  \
    cur ^= 1;                                                                  \
}

// ---- main attention: 2-deep per-wave pipeline; K LDS dbuf, V->regs ----
__global__ __launch_bounds__(256, 2) void attn_fwd(
    const float* __restrict__ Q, const unsigned short* __restrict__ Kt,
    const unsigned short* __restrict__ Vt, float* __restrict__ O)
{
    __shared__ __align__(16) unsigned short klds[2][4096];

    const int L = blockIdx.x;              // 1024 blocks
    const int xcd = L & 7;
    const int j = L >> 3;                  // 0..127
    const int head = xcd + 8 * (j >> 4);   // all 16 q-blocks of a head on one XCD
    const int qt = j & 15;
    const int b = head >> 4, h = head & 15;

    const int tid  = threadIdx.x;
    const int wave = tid >> 6;
    const int lane = tid & 63;
    const int l31  = lane & 31;
    const int hi   = lane >> 5;

    const unsigned short* kbase = Kt + (size_t)head * (NT * 4096);
    const unsigned short* vbase = Vt + (size_t)head * (NT * 4096);
    const float* qp = Q + (size_t)b * N_ * C_ + (size_t)h * 64;
    float*       op = O + (size_t)b * N_ * C_ + (size_t)h * 64;

    // Q B-fragments
    const int qrow = qt * 128 + wave * 32 + l31;
    short8 qfrag[4];
    {
        const float* qr = qp + (size_t)qrow * C_ + hi * 8;
        #pragma unroll
        for (int ks = 0; ks < 4; ++ks) {
            f32x4 x0 = *(const f32x4*)(qr + ks * 16);
            f32x4 x1 = *(const f32x4*)(qr + ks * 16 + 4);
            short8 a;
            #pragma unroll
            for (int i = 0; i < 4; ++i) {
                a[i]     = (short)f2bf(x0[i] * QSCALE);
                a[i + 4] = (short)f2bf(x1[i] * QSCALE);
            }
            qfrag[ks] = a;
        }
    }

    f32x16 o0 = {}, o1 = {};
    f32x16 sX0, sX1, sY0, sY1;
    float m_r = 0.0f, l_half = 0.0f;

    const int lofs = lane * 8;

    auto stageK = [&](int t, int buf) {
        const unsigned short* kg = kbase + (size_t)t * 4096 + wave * 1024 + lofs;
        __builtin_amdgcn_global_load_lds((const __attribute__((address_space(1))) void*)kg,
            (__attribute__((address_space(3))) void*)&klds[buf][wave * 1024], 16, 0, 0);
        __builtin_amdgcn_global_load_lds((const __attribute__((address_space(1))) void*)(kg + 512),
            (__attribute__((address_space(3))) void*)&klds[buf][wave * 1024 + 512], 16, 0, 0);
    };

    int cur = 0;
    short8 pf0, pf1, pf2, pf3;
    short8 vr0, vr1, vr2, vr3, vr4, vr5, vr6, vr7;

    stageK(0, 0);
    asm volatile("s_waitcnt vmcnt(0) lgkmcnt(0)" ::: "memory");
    __syncthreads();

    // ---- body 0 (peeled): QK(0) -> sX, V(0) -> vr; no softmax/PV yet ----
    {
        stageK(1, 1);
        m_r = 0.0f;           // sX C-init = 0 via nm = -m_r
        QK_SECTION(sX0, sX1)
        V_LOAD(0)
        cur ^= 1;
    }

    // ---- body 1 (softmax-first on tile 0) ----
    TILE_BODY2(1, sY0, sY1, sX0, sX1, 1)

    // ---- steady state ----
    for (int t = 2; t < 31; t += 2) {
        TILE_BODY2(t,     sX0, sX1, sY0, sY1, 0)
        TILE_BODY2(t + 1, sY0, sY1, sX0, sX1, 0)
    }

    // ---- epilogue: softmax(31) on sY + final PV(31) ----
    SM_HEAD(sY0, sY1, 0)
    SM_TAIL(sY0, sY1)
    PV_SECTION()

    int2v lsw = __builtin_amdgcn_permlane32_swap(
        __float_as_int(l_half), __float_as_int(l_half), false, false);
    const float l_r = __int_as_float(lsw[0]) + __int_as_float(lsw[1]);
    const float inv = 1.0f / l_r;

    float* orow = op + (size_t)qrow * C_;
    #pragma unroll
    for (int bb = 0; bb < 4; ++bb) {
        f32x4 w0, w1;
        #pragma unroll
        for (int i = 0; i < 4; ++i) {
            w0[i] = o0[4 * bb + i] * inv;
            w1[i] = o1[4 * bb + i] * inv;
        }
        *(f32x4*)(orow + 8 * bb + 4 * hi)      = w0;   // d = bb*8 + hi*4 + i
        *(f32x4*)(orow + 32 + 8 * bb + 4 * hi) = w1;
    }
}

extern "C" void kernel_launch(void* const* d_in, const int* in_sizes, int n_in,
                              void* d_out, int out_size, void* d_ws, size_t ws_size,
                              hipStream_t stream) {
    const float* q = (const float*)d_in[0];
    const float* k = (const float*)d_in[1];
    const float* v = (const float*)d_in[2];
    float* o = (float*)d_out;
    unsigned short* Kt = (unsigned short*)d_ws;                 // 16 MB
    unsigned short* Vt = Kt + (size_t)64 * NT * 4096;           // +16 MB
    prepack<<<dim3(64 * NT), dim3(256), 0, stream>>>(k, v, Kt, Vt);
    attn_fwd<<<dim3(1024), dim3(256), 0, stream>>>(q, Kt, Vt, o);
}

// Round 15
// 109.075 us; speedup vs baseline: 1.9374x; 1.9374x over previous
//
#include <hip/hip_runtime.h>
#include <hip/hip_bf16.h>

#define B_   4
#define N_   2048
#define C_   1024
#define NT   32
#define QSCALE 0.18033688011112042f   // 0.125 * log2(e)

typedef __attribute__((ext_vector_type(8)))  short short8;
typedef __attribute__((ext_vector_type(4)))  float f32x4;
typedef __attribute__((ext_vector_type(16))) float f32x16;
typedef __attribute__((ext_vector_type(2)))  int   int2v;

__device__ __forceinline__ unsigned short f2bf(float x) {
    union { __hip_bfloat16 h; unsigned short u; } c;
    c.h = __float2bfloat16(x);
    return c.u;
}
__device__ __forceinline__ float fast_exp2(float x) {
    float r; asm("v_exp_f32 %0, %1" : "=v"(r) : "v"(x)); return r;
}
__device__ __forceinline__ int cvtpk(float a, float b) {
    int r; asm("v_cvt_pk_bf16_f32 %0, %1, %2" : "=v"(r) : "v"(a), "v"(b)); return r;
}

// ---- pre-pass: f32 [B,N,C] -> bf16 tiles in MFMA-FRAGMENT order ----
// Per (head,tile) 8KB image, fragment f (0..7), cell c = f*64 + lane:
//   row = (f&1)*32 + (lane&31), col = (f>>1)*16 + (lane>>5)*8 .. +8
__global__ __launch_bounds__(256) void prepack(
    const float* __restrict__ K, const float* __restrict__ V,
    unsigned short* __restrict__ Kt, unsigned short* __restrict__ Vt)
{
    __shared__ __align__(16) unsigned short kl[4096];
    __shared__ __align__(16) unsigned short vl[4096];
    const int L = blockIdx.x;              // 2048
    const int xcd = L & 7;
    const int j = L >> 3;                  // 0..255
    const int head = xcd + 8 * (j >> 5);   // same head->XCD map as attn
    const int t = j & 31;
    const int b = head >> 4, h = head & 15;
    const int tid = threadIdx.x;
    const int r = tid >> 2, cb = tid & 3;
    const size_t head_off = (size_t)b * N_ * C_ + (size_t)h * 64;
    const int kv0 = t * 64;
    const int blk_out = head * NT + t;

    {
        const float* src = K + head_off + (size_t)(kv0 + r) * C_ + cb * 16;
        f32x4 x0 = *(const f32x4*)(src);
        f32x4 x1 = *(const f32x4*)(src + 4);
        f32x4 x2 = *(const f32x4*)(src + 8);
        f32x4 x3 = *(const f32x4*)(src + 12);
        short8 p0, p1;
        #pragma unroll
        for (int i = 0; i < 4; ++i) {
            p0[i] = (short)f2bf(x0[i]); p0[i + 4] = (short)f2bf(x1[i]);
            p1[i] = (short)f2bf(x2[i]); p1[i + 4] = (short)f2bf(x3[i]);
        }
        const int swz = (r & 7) << 3;
        *(short8*)&kl[r * 64 + ((cb * 16) ^ swz)]     = p0;
        *(short8*)&kl[r * 64 + ((cb * 16 + 8) ^ swz)] = p1;
    }
    {
        const float* src = V + head_off + (size_t)(kv0 + r) * C_ + cb * 16;
        f32x4 y0 = *(const f32x4*)(src);
        f32x4 y1 = *(const f32x4*)(src + 4);
        f32x4 y2 = *(const f32x4*)(src + 8);
        f32x4 y3 = *(const f32x4*)(src + 12);
        #pragma unroll
        for (int i = 0; i < 4; ++i) {
            int d0 = cb * 16 + i;
            vl[d0 * 64 + (r ^ ((d0 & 7) << 3))] = f2bf(y0[i]);
            int d1 = cb * 16 + 4 + i;
            vl[d1 * 64 + (r ^ ((d1 & 7) << 3))] = f2bf(y1[i]);
            int d2 = cb * 16 + 8 + i;
            vl[d2 * 64 + (r ^ ((d2 & 7) << 3))] = f2bf(y2[i]);
            int d3 = cb * 16 + 12 + i;
            vl[d3 * 64 + (r ^ ((d3 & 7) << 3))] = f2bf(y3[i]);
        }
    }
    __syncthreads();
    #pragma unroll
    for (int cc = 0; cc < 2; ++cc) {
        const int c  = tid + cc * 256;
        const int f  = c >> 6;
        const int ln = c & 63;
        const int row = (f & 1) * 32 + (ln & 31);
        const int col = (f >> 1) * 16 + (ln >> 5) * 8;
        const int sw  = (row & 7) << 3;
        short8 kk = *(const short8*)&kl[row * 64 + (col ^ sw)];
        short8 vv = *(const short8*)&vl[row * 64 + (col ^ sw)];
        *(short8*)&Kt[(size_t)blk_out * 4096 + c * 8] = kk;
        *(short8*)&Vt[(size_t)blk_out * 4096 + c * 8] = vv;
    }
}

#define MFMA32(A, B, C) __builtin_amdgcn_mfma_f32_32x32x16_bf16((A), (B), (C), 0, 0, 0)

// one K/V tile; PO*/PI* are NAMED short8 variables (token-pasted, no arrays)
// T4: counted vmcnt(8) retires only the 2 stage-K ops (oldest in queue);
// the 8 V register-loads stay in flight across the raw s_barrier.
#define TILE_BODY(T, PO0, PO1, PO2, PO3, PI0, PI1, PI2, PI3, FIRST)            \
{                                                                              \
    if ((T) == 0) { asm volatile("s_waitcnt vmcnt(0)" ::: "memory"); }         \
    else          { asm volatile("s_waitcnt vmcnt(8)" ::: "memory"); }         \
    __builtin_amdgcn_s_barrier();                                              \
    if ((T) + 1 < NT) stageK((T) + 1, cur ^ 1);                                \
    const unsigned short* kl = &klds[cur][0];                                  \
    f32x16 s0, s1;                                                             \
    {                                                                          \
        const float nm = (FIRST) ? 0.0f : -m_r;  /* shift baked into C-init */ \
        _Pragma("unroll")                                                      \
        for (int r = 0; r < 16; ++r) { s0[r] = nm; s1[r] = nm; }               \
    }                                                                          \
    __builtin_amdgcn_s_setprio(1);                                             \
    {                                                                          \
        short8 kf0 = *(const short8*)&kl[0 * 1024 + lofs];                     \
        short8 kf1 = *(const short8*)&kl[0 * 1024 + 512 + lofs];               \
        s0 = MFMA32(kf0, qfrag[0], s0);                                        \
        s1 = MFMA32(kf1, qfrag[0], s1);                                        \
        kf0 = *(const short8*)&kl[1 * 1024 + lofs];                            \
        kf1 = *(const short8*)&kl[1 * 1024 + 512 + lofs];                      \
        s0 = MFMA32(kf0, qfrag[1], s0);                                        \
        s1 = MFMA32(kf1, qfrag[1], s1);                                        \
        kf0 = *(const short8*)&kl[2 * 1024 + lofs];                            \
        kf1 = *(const short8*)&kl[2 * 1024 + 512 + lofs];                      \
        s0 = MFMA32(kf0, qfrag[2], s0);                                        \
        s1 = MFMA32(kf1, qfrag[2], s1);                                        \
        kf0 = *(const short8*)&kl[3 * 1024 + lofs];                            \
        kf1 = *(const short8*)&kl[3 * 1024 + 512 + lofs];                      \
        s0 = MFMA32(kf0, qfrag[3], s0);                                        \
        s1 = MFMA32(kf1, qfrag[3], s1);                                        \
    }                                                                          \
    if (!(FIRST)) {   /* PV(t-1): queued on matrix pipe, overlaps softmax */   \
        o0 = MFMA32(vr0, PI0, o0);  o1 = MFMA32(vr1, PI0, o1);                 \
        o0 = MFMA32(vr2, PI1, o0);  o1 = MFMA32(vr3, PI1, o1);                 \
        o0 = MFMA32(vr4, PI2, o0);  o1 = MFMA32(vr5, PI2, o1);                 \
        o0 = MFMA32(vr6, PI3, o0);  o1 = MFMA32(vr7, PI3, o1);                 \
    }                                                                          \
    __builtin_amdgcn_s_setprio(0);                                             \
    {   /* V(T) -> named regs, consumed by PV in next iteration */             \
        const unsigned short* vtp = vbase + (size_t)(T) * 4096 + lofs;         \
        vr0 = *(const short8*)(vtp);                                           \
        vr1 = *(const short8*)(vtp + 512);                                     \
        vr2 = *(const short8*)(vtp + 1024);                                    \
        vr3 = *(const short8*)(vtp + 1536);                                    \
        vr4 = *(const short8*)(vtp + 2048);                                    \
        vr5 = *(const short8*)(vtp + 2560);                                    \
        vr6 = *(const short8*)(vtp + 3072);                                    \
        vr7 = *(const short8*)(vtp + 3584);                                    \
    }                                                                          \
    float mx[8];                                                               \
    _Pragma("unroll")                                                          \
    for (int r = 0; r < 8; ++r)                                                \
        mx[r] = fmaxf(fmaxf(s0[r], s0[r + 8]), fmaxf(s1[r], s1[r + 8]));       \
    _Pragma("unroll")                                                          \
    for (int st = 4; st; st >>= 1) {                                           \
        _Pragma("unroll")                                                      \
        for (int r = 0; r < st; ++r) mx[r] = fmaxf(mx[r], mx[r + st]);         \
    }                                                                          \
    int2v msw = __builtin_amdgcn_permlane32_swap(                              \
        __float_as_int(mx[0]), __float_as_int(mx[0]), false, false);           \
    const float rmp = fmaxf(__int_as_float(msw[0]), __int_as_float(msw[1]));   \
    if (FIRST) {                                                               \
        m_r = rmp;                                                             \
        _Pragma("unroll")                                                      \
        for (int r = 0; r < 16; ++r) { s0[r] -= rmp; s1[r] -= rmp; }           \
    } else if (!__all(rmp <= 8.0f)) {    /* T13 defer-max rare path */         \
        const float d = fmaxf(rmp, 0.0f);                                      \
        const float corr = fast_exp2(-d);                                      \
        m_r += d;                                                              \
        l_half *= corr;                                                        \
        _Pragma("unroll")                                                      \
        for (int r = 0; r < 16; ++r) {                                         \
            s0[r] -= d; s1[r] -= d;                                            \
            o0[r] *= corr; o1[r] *= corr;                                      \
        }                                                                      \
    }                                                                          \
    _Pragma("unroll")                                                          \
    for (int r = 0; r < 16; ++r) {                                             \
        s0[r] = fast_exp2(s0[r]);                                              \
        s1[r] = fast_exp2(s1[r]);                                              \
    }                                                                          \
    {   /* T12 pack: s0 -> PO0/PO1, s1 -> PO2/PO3 */                           \
        int w0, w1, w2, w3; int2v sA, sB;                                      \
        union { int i[4]; short8 v; } u;                                       \
        w0 = cvtpk(s0[0], s0[1]);  w1 = cvtpk(s0[2], s0[3]);                   \
        w2 = cvtpk(s0[4], s0[5]);  w3 = cvtpk(s0[6], s0[7]);                   \
        sA = __builtin_amdgcn_permlane32_swap(w0, w2, false, false);           \
        sB = __builtin_amdgcn_permlane32_swap(w1, w3, false, false);           \
        u.i[0] = sA[0]; u.i[1] = sB[0]; u.i[2] = sA[1]; u.i[3] = sB[1];        \
        PO0 = u.v;                                                             \
        w0 = cvtpk(s0[8], s0[9]);  w1 = cvtpk(s0[10], s0[11]);                 \
        w2 = cvtpk(s0[12], s0[13]); w3 = cvtpk(s0[14], s0[15]);                \
        sA = __builtin_amdgcn_permlane32_swap(w0, w2, false, false);           \
        sB = __builtin_amdgcn_permlane32_swap(w1, w3, false, false);           \
        u.i[0] = sA[0]; u.i[1] = sB[0]; u.i[2] = sA[1]; u.i[3] = sB[1];        \
        PO1 = u.v;                                                             \
        w0 = cvtpk(s1[0], s1[1]);  w1 = cvtpk(s1[2], s1[3]);                   \
        w2 = cvtpk(s1[4], s1[5]);  w3 = cvtpk(s1[6], s1[7]);                   \
        sA = __builtin_amdgcn_permlane32_swap(w0, w2, false, false);           \
        sB = __builtin_amdgcn_permlane32_swap(w1, w3, false, false);           \
        u.i[0] = sA[0]; u.i[1] = sB[0]; u.i[2] = sA[1]; u.i[3] = sB[1];        \
        PO2 = u.v;                                                             \
        w0 = cvtpk(s1[8], s1[9]);  w1 = cvtpk(s1[10], s1[11]);                 \
        w2 = cvtpk(s1[12], s1[13]); w3 = cvtpk(s1[14], s1[15]);                \
        sA = __builtin_amdgcn_permlane32_swap(w0, w2, false, false);           \
        sB = __builtin_amdgcn_permlane32_swap(w1, w3, false, false);           \
        u.i[0] = sA[0]; u.i[1] = sB[0]; u.i[2] = sA[1]; u.i[3] = sB[1];        \
        PO3 = u.v;                                                             \
    }                                                                          \
    float aa[8];                                                               \
    _Pragma("unroll")                                                          \
    for (int r = 0; r < 8; ++r) aa[r] = (s0[r] + s0[r + 8]) + (s1[r] + s1[r + 8]); \
    _Pragma("unroll")                                                          \
    for (int st = 4; st; st >>= 1) {                                           \
        _Pragma("unroll")                                                      \
        for (int r = 0; r < st; ++r) aa[r] += aa[r + st];                      \
    }                                                                          \
    l_half += aa[0];                                                           \
    cur ^= 1;                                                                  \
}

// ---- main attention: K LDS dbuf, V global->reg one tile ahead, deferred PV ----
__global__ __launch_bounds__(256, 3) void attn_fwd(
    const float* __restrict__ Q, const unsigned short* __restrict__ Kt,
    const unsigned short* __restrict__ Vt, float* __restrict__ O)
{
    __shared__ __align__(16) unsigned short klds[2][4096];

    const int L = blockIdx.x;              // 1024 blocks
    const int xcd = L & 7;
    const int j = L >> 3;                  // 0..127
    const int head = xcd + 8 * (j >> 4);   // all 16 q-blocks of a head on one XCD
    const int qt = j & 15;
    const int b = head >> 4, h = head & 15;

    const int tid  = threadIdx.x;
    const int wave = tid >> 6;
    const int lane = tid & 63;
    const int l31  = lane & 31;
    const int hi   = lane >> 5;

    const unsigned short* kbase = Kt + (size_t)head * (NT * 4096);
    const unsigned short* vbase = Vt + (size_t)head * (NT * 4096);
    const float* qp = Q + (size_t)b * N_ * C_ + (size_t)h * 64;
    float*       op = O + (size_t)b * N_ * C_ + (size_t)h * 64;

    // Q B-fragments: col q = qt*128 + wave*32 + l31, k = ks*16 + hi*8 + j
    const int qrow = qt * 128 + wave * 32 + l31;
    short8 qfrag[4];
    {
        const float* qr = qp + (size_t)qrow * C_ + hi * 8;
        #pragma unroll
        for (int ks = 0; ks < 4; ++ks) {
            f32x4 x0 = *(const f32x4*)(qr + ks * 16);
            f32x4 x1 = *(const f32x4*)(qr + ks * 16 + 4);
            short8 a;
            #pragma unroll
            for (int i = 0; i < 4; ++i) {
                a[i]     = (short)f2bf(x0[i] * QSCALE);
                a[i + 4] = (short)f2bf(x1[i] * QSCALE);
            }
            qfrag[ks] = a;
        }
    }

    f32x16 o0 = {}, o1 = {};
    float m_r = 0.0f, l_half = 0.0f;

    const int lofs = lane * 8;

    auto stageK = [&](int t, int buf) {
        const unsigned short* kg = kbase + (size_t)t * 4096 + wave * 1024 + lofs;
        __builtin_amdgcn_global_load_lds((const __attribute__((address_space(1))) void*)kg,
            (__attribute__((address_space(3))) void*)&klds[buf][wave * 1024], 16, 0, 0);
        __builtin_amdgcn_global_load_lds((const __attribute__((address_space(1))) void*)(kg + 512),
            (__attribute__((address_space(3))) void*)&klds[buf][wave * 1024 + 512], 16, 0, 0);
    };

    int cur = 0;
    short8 pA0, pA1, pA2, pA3, pB0, pB1, pB2, pB3;
    short8 vr0, vr1, vr2, vr3, vr4, vr5, vr6, vr7;

    stageK(0, 0);

    TILE_BODY(0, pA0, pA1, pA2, pA3, pB0, pB1, pB2, pB3, true)
    for (int t = 1; t < NT - 1; t += 2) {
        TILE_BODY(t,     pB0, pB1, pB2, pB3, pA0, pA1, pA2, pA3, false)
        TILE_BODY(t + 1, pA0, pA1, pA2, pA3, pB0, pB1, pB2, pB3, false)
    }
    TILE_BODY(NT - 1, pB0, pB1, pB2, pB3, pA0, pA1, pA2, pA3, false)

    // final PV(NT-1)
    __builtin_amdgcn_s_setprio(1);
    o0 = MFMA32(vr0, pB0, o0);  o1 = MFMA32(vr1, pB0, o1);
    o0 = MFMA32(vr2, pB1, o0);  o1 = MFMA32(vr3, pB1, o1);
    o0 = MFMA32(vr4, pB2, o0);  o1 = MFMA32(vr5, pB2, o1);
    o0 = MFMA32(vr6, pB3, o0);  o1 = MFMA32(vr7, pB3, o1);
    __builtin_amdgcn_s_setprio(0);

    // epilogue: combine denominator halves once, normalize, store
    int2v lsw = __builtin_amdgcn_permlane32_swap(
        __float_as_int(l_half), __float_as_int(l_half), false, false);
    const float l_r = __int_as_float(lsw[0]) + __int_as_float(lsw[1]);
    const float inv = 1.0f / l_r;

    float* orow = op + (size_t)qrow * C_;
    #pragma unroll
    for (int bb = 0; bb < 4; ++bb) {
        f32x4 w0, w1;
        #pragma unroll
        for (int i = 0; i < 4; ++i) {
            w0[i] = o0[4 * bb + i] * inv;
            w1[i] = o1[4 * bb + i] * inv;
        }
        *(f32x4*)(orow + 8 * bb + 4 * hi)      = w0;   // d = bb*8 + 4*hi + i
        *(f32x4*)(orow + 32 + 8 * bb + 4 * hi) = w1;
    }
}

extern "C" void kernel_launch(void* const* d_in, const int* in_sizes, int n_in,
                              void* d_out, int out_size, void* d_ws, size_t ws_size,
                              hipStream_t stream) {
    const float* q = (const float*)d_in[0];
    const float* k = (const float*)d_in[1];
    const float* v = (const float*)d_in[2];
    float* o = (float*)d_out;
    unsigned short* Kt = (unsigned short*)d_ws;                 // 16 MB
    unsigned short* Vt = Kt + (size_t)64 * NT * 4096;           // +16 MB
    prepack<<<dim3(64 * NT), dim3(256), 0, stream>>>(k, v, Kt, Vt);
    attn_fwd<<<dim3(1024), dim3(256), 0, stream>>>(q, Kt, Vt, o);
}